// Round 13
// baseline (244.287 us; speedup 1.0000x reference)
//
#include <hip/hip_runtime.h>

constexpr int N_NODES = 50000;
constexpr int N_EDGES = 800000;
constexpr int D = 128;
constexpr float ALPHA = 0.2f;
constexpr int SCAN_NBLK = (N_NODES + 255) / 256; // 196
constexpr int NXCD = 8;
constexpr int NODES_PER_G = N_NODES / NXCD;      // 6250 (divides evenly)
constexpr int EDGE_NBLK = (N_EDGES + 255) / 256; // 3125
constexpr int FUSE_NBLK = 196 * NXCD;            // 1568: gemm+hist fused grid
constexpr int HIST_STRIDE = FUSE_NBLK / NXCD;    // 196

__device__ __forceinline__ void fma4(float4& acc, float s, const float4& w) {
    acc.x += s * w.x; acc.y += s * w.y; acc.z += s * w.z; acc.w += s * w.w;
}
__device__ __forceinline__ float dot4(const float4& x, const float4& y) {
    return x.x * y.x + x.y * y.y + x.z * y.z + x.w * y.w;
}
// pack two fp32 -> two bf16 (RNE) in one uint: low16 = a, high16 = b
__device__ __forceinline__ unsigned bf16pack2(float a, float b) {
    unsigned ua = __float_as_uint(a); ua += 0x7FFFu + ((ua >> 16) & 1u);
    unsigned ub = __float_as_uint(b); ub += 0x7FFFu + ((ub >> 16) & 1u);
    return (ua >> 16) | (ub & 0xFFFF0000u);
}
__device__ __forceinline__ float bf16lo(unsigned p) { return __uint_as_float(p << 16); }
__device__ __forceinline__ float bf16hi(unsigned p) { return __uint_as_float(p & 0xFFFF0000u); }

// ---------------------------------------------------------------------------
// K1: fused  (a) h_bf16 = bf16(feat @ W + bias), s_src/s_dst scores
//            (b) histogram of edges by src (XCD-range-partitioned)
// W staged in LDS as bf16 (32 KB) -> 4 blocks/CU (16 waves/CU) vs 2 at 64 KB.
// Grid 1568 = 8*196: block b serves XCD-group g=b&7, hist stride 196 covers
// all 3125 edge-blocks per g.
// ---------------------------------------------------------------------------
__global__ __launch_bounds__(256, 4)
void k_gemm_hist(const float* __restrict__ feat,
                 const float* __restrict__ W,
                 const float* __restrict__ a,
                 const float* __restrict__ bias,
                 uint2* __restrict__ hb,
                 float* __restrict__ s_src,
                 float* __restrict__ s_dst,
                 const int* __restrict__ adj,
                 int* __restrict__ counts)
{
    __shared__ uint2 w_lds[D * 32];                  // 32 KB: [k][cg] bf16x4
    const int tid = threadIdx.x;
    const float4* W4 = reinterpret_cast<const float4*>(W);
    #pragma unroll
    for (int i = 0; i < 16; ++i) {
        const float4 w = W4[tid + i * 256];
        w_lds[tid + i * 256] = make_uint2(bf16pack2(w.x, w.y), bf16pack2(w.z, w.w));
    }
    __syncthreads();

    const int cg = tid & 31;                         // column group (4 cols)
    const int ng = tid >> 5;                         // node group 0..7
    const int n0 = blockIdx.x * 32 + ng * 4;

    const float4 a_s = reinterpret_cast<const float4*>(a)[cg];
    const float4 a_d = reinterpret_cast<const float4*>(a)[32 + cg];
    const float4 b4  = reinterpret_cast<const float4*>(bias)[cg];

    // clamp row pointers so tail threads read in-bounds (stores are guarded)
    const float4* fA = reinterpret_cast<const float4*>(feat) + (long long)min(n0 + 0, N_NODES - 1) * 32;
    const float4* fB = reinterpret_cast<const float4*>(feat) + (long long)min(n0 + 1, N_NODES - 1) * 32;
    const float4* fC = reinterpret_cast<const float4*>(feat) + (long long)min(n0 + 2, N_NODES - 1) * 32;
    const float4* fD = reinterpret_cast<const float4*>(feat) + (long long)min(n0 + 3, N_NODES - 1) * 32;

    float4 acc0 = {0.f, 0.f, 0.f, 0.f};
    float4 acc1 = {0.f, 0.f, 0.f, 0.f};
    float4 acc2 = {0.f, 0.f, 0.f, 0.f};
    float4 acc3 = {0.f, 0.f, 0.f, 0.f};

    #pragma unroll 4
    for (int kc = 0; kc < 32; ++kc) {                // 4 k-values per chunk
        const float4 fa = fA[kc];
        const float4 fb = fB[kc];
        const float4 fc = fC[kc];
        const float4 fd = fD[kc];
        const uint2 p0 = w_lds[(kc * 4 + 0) * 32 + cg];
        const uint2 p1 = w_lds[(kc * 4 + 1) * 32 + cg];
        const uint2 p2 = w_lds[(kc * 4 + 2) * 32 + cg];
        const uint2 p3 = w_lds[(kc * 4 + 3) * 32 + cg];
        const float4 w0 = {bf16lo(p0.x), bf16hi(p0.x), bf16lo(p0.y), bf16hi(p0.y)};
        const float4 w1 = {bf16lo(p1.x), bf16hi(p1.x), bf16lo(p1.y), bf16hi(p1.y)};
        const float4 w2 = {bf16lo(p2.x), bf16hi(p2.x), bf16lo(p2.y), bf16hi(p2.y)};
        const float4 w3 = {bf16lo(p3.x), bf16hi(p3.x), bf16lo(p3.y), bf16hi(p3.y)};
        fma4(acc0, fa.x, w0); fma4(acc0, fa.y, w1); fma4(acc0, fa.z, w2); fma4(acc0, fa.w, w3);
        fma4(acc1, fb.x, w0); fma4(acc1, fb.y, w1); fma4(acc1, fb.z, w2); fma4(acc1, fb.w, w3);
        fma4(acc2, fc.x, w0); fma4(acc2, fc.y, w1); fma4(acc2, fc.z, w2); fma4(acc2, fc.w, w3);
        fma4(acc3, fd.x, w0); fma4(acc3, fd.y, w1); fma4(acc3, fd.z, w2); fma4(acc3, fd.w, w3);
    }

    acc0.x += b4.x; acc0.y += b4.y; acc0.z += b4.z; acc0.w += b4.w;
    acc1.x += b4.x; acc1.y += b4.y; acc1.z += b4.z; acc1.w += b4.w;
    acc2.x += b4.x; acc2.y += b4.y; acc2.z += b4.z; acc2.w += b4.w;
    acc3.x += b4.x; acc3.y += b4.y; acc3.z += b4.z; acc3.w += b4.w;

    if (n0 + 0 < N_NODES) hb[(long long)(n0 + 0) * 32 + cg] = make_uint2(bf16pack2(acc0.x, acc0.y), bf16pack2(acc0.z, acc0.w));
    if (n0 + 1 < N_NODES) hb[(long long)(n0 + 1) * 32 + cg] = make_uint2(bf16pack2(acc1.x, acc1.y), bf16pack2(acc1.z, acc1.w));
    if (n0 + 2 < N_NODES) hb[(long long)(n0 + 2) * 32 + cg] = make_uint2(bf16pack2(acc2.x, acc2.y), bf16pack2(acc2.z, acc2.w));
    if (n0 + 3 < N_NODES) hb[(long long)(n0 + 3) * 32 + cg] = make_uint2(bf16pack2(acc3.x, acc3.y), bf16pack2(acc3.z, acc3.w));

    float ps0 = dot4(acc0, a_s), pd0 = dot4(acc0, a_d);
    float ps1 = dot4(acc1, a_s), pd1 = dot4(acc1, a_d);
    float ps2 = dot4(acc2, a_s), pd2 = dot4(acc2, a_d);
    float ps3 = dot4(acc3, a_s), pd3 = dot4(acc3, a_d);
    #pragma unroll
    for (int m = 1; m < 32; m <<= 1) {               // reduce across the 32-lane group
        ps0 += __shfl_xor(ps0, m); pd0 += __shfl_xor(pd0, m);
        ps1 += __shfl_xor(ps1, m); pd1 += __shfl_xor(pd1, m);
        ps2 += __shfl_xor(ps2, m); pd2 += __shfl_xor(pd2, m);
        ps3 += __shfl_xor(ps3, m); pd3 += __shfl_xor(pd3, m);
    }
    if (cg == 0) {
        if (n0 + 0 < N_NODES) { s_src[n0 + 0] = ps0; s_dst[n0 + 0] = pd0; }
        if (n0 + 1 < N_NODES) { s_src[n0 + 1] = ps1; s_dst[n0 + 1] = pd1; }
        if (n0 + 2 < N_NODES) { s_src[n0 + 2] = ps2; s_dst[n0 + 2] = pd2; }
        if (n0 + 3 < N_NODES) { s_src[n0 + 3] = ps3; s_dst[n0 + 3] = pd3; }
    }

    // ---- hist phase (independent of gemm phase; no barrier needed) ----
    const int g = blockIdx.x & (NXCD - 1);
    for (int eb = blockIdx.x >> 3; eb < EDGE_NBLK; eb += HIST_STRIDE) {
        const int i = eb * 256 + tid;
        if (i < N_EDGES) {
            const int s = adj[i];
            if ((unsigned)(s - g * NODES_PER_G) < (unsigned)NODES_PER_G)
                atomicAdd(&counts[s], 1);
        }
    }
}

// ---------------------------------------------------------------------------
// Block-wide inclusive scan of one int per thread (256 threads = 4 waves)
// ---------------------------------------------------------------------------
__device__ __forceinline__ int block_incl_scan(int v, int tid)
{
    __shared__ int wsum[4];
    const int lane = tid & 63;
    int x = v;
    #pragma unroll
    for (int off = 1; off < 64; off <<= 1) {
        const int y = __shfl_up(x, off);
        if (lane >= off) x += y;
    }
    if (lane == 63) wsum[tid >> 6] = x;
    __syncthreads();
    const int w = tid >> 6;
    int base = 0;
    #pragma unroll
    for (int k = 0; k < 3; ++k)
        if (k < w) base += wsum[k];
    return x + base;
}

// K2b-1: per-block inclusive scan; write inclusive values + block sums
__global__ __launch_bounds__(256)
void k_scan1(const int* __restrict__ counts,
             int* __restrict__ incl,
             int* __restrict__ bsum)
{
    const int i = blockIdx.x * 256 + threadIdx.x;
    const int v = (i < N_NODES) ? counts[i] : 0;
    const int x = block_incl_scan(v, threadIdx.x);
    if (i < N_NODES) incl[i] = x;
    if (threadIdx.x == 255) bsum[blockIdx.x] = x;
}

// K2b-2: row_start = incl - count + block_base. Each block re-scans the 196
// block sums locally (cheap) -> no separate scan2 kernel / launch gap.
__global__ __launch_bounds__(256)
void k_scan3(const int* __restrict__ incl,
             const int* __restrict__ counts,
             const int* __restrict__ bsum,
             int* __restrict__ row_start,
             int* __restrict__ cursor)
{
    __shared__ int sbase;
    const int t = threadIdx.x;
    const int v = (t < SCAN_NBLK) ? bsum[t] : 0;
    const int x = block_incl_scan(v, t);
    if (t == blockIdx.x) sbase = x - v;              // exclusive prefix at t
    __syncthreads();
    const int i = blockIdx.x * 256 + t;
    if (i < N_NODES) {
        const int e = incl[i] - counts[i] + sbase;
        row_start[i] = e;
        cursor[i]    = e;
    }
}

// ---------------------------------------------------------------------------
// K2c: bucket fill — XCD-range-partitioned (see round-9 note).
// ---------------------------------------------------------------------------
__global__ __launch_bounds__(256)
void k_fill(const int* __restrict__ adj,
            int* __restrict__ cursor,
            int* __restrict__ col)
{
    const int g  = blockIdx.x & (NXCD - 1);
    const int eb = blockIdx.x >> 3;
    const int i  = eb * 256 + threadIdx.x;
    if (i >= N_EDGES) return;
    const int s = adj[i];
    if ((unsigned)(s - g * NODES_PER_G) < (unsigned)NODES_PER_G) {
        const int d = adj[N_EDGES + i];
        const int pos = atomicAdd(&cursor[s], 1);
        col[pos] = d;
    }
}

// ---------------------------------------------------------------------------
// K3: gather — out[n] = sum over edges(n) of leaky(ss[n]+sd[dst]) * h[dst]
// h rows are bf16 (256 B): 32 lanes x uint2 (4 bf16 each). fp32 accumulate.
// ---------------------------------------------------------------------------
__global__ __launch_bounds__(256)
void k_gather(const int* __restrict__ row_start,
              const int* __restrict__ cursor,
              const int* __restrict__ col,
              const float* __restrict__ s_src,
              const float* __restrict__ s_dst,
              const uint2* __restrict__ hb,
              float* __restrict__ out)
{
    const int tid  = threadIdx.x;
    const int cg   = tid & 31;
    const int node = blockIdx.x * 8 + (tid >> 5);
    const int beg  = row_start[node];
    const int end  = cursor[node];
    const float ss = s_src[node];

    float4 acc = {0.f, 0.f, 0.f, 0.f};
    int j = beg;
    for (; j + 1 < end; j += 2) {
        const int d0 = col[j];
        const int d1 = col[j + 1];
        const float x0 = ss + s_dst[d0];
        const float x1 = ss + s_dst[d1];
        const float e0 = x0 > 0.f ? x0 : ALPHA * x0;
        const float e1 = x1 > 0.f ? x1 : ALPHA * x1;
        const uint2 p0 = hb[(long long)d0 * 32 + cg];
        const uint2 p1 = hb[(long long)d1 * 32 + cg];
        acc.x += e0 * bf16lo(p0.x) + e1 * bf16lo(p1.x);
        acc.y += e0 * bf16hi(p0.x) + e1 * bf16hi(p1.x);
        acc.z += e0 * bf16lo(p0.y) + e1 * bf16lo(p1.y);
        acc.w += e0 * bf16hi(p0.y) + e1 * bf16hi(p1.y);
    }
    if (j < end) {
        const int d0 = col[j];
        const float x0 = ss + s_dst[d0];
        const float e0 = x0 > 0.f ? x0 : ALPHA * x0;
        const uint2 p0 = hb[(long long)d0 * 32 + cg];
        acc.x += e0 * bf16lo(p0.x);
        acc.y += e0 * bf16hi(p0.x);
        acc.z += e0 * bf16lo(p0.y);
        acc.w += e0 * bf16hi(p0.y);
    }
    reinterpret_cast<float4*>(out)[(long long)node * 32 + cg] = acc;
}

// ---------------------------------------------------------------------------
extern "C" void kernel_launch(void* const* d_in, const int* in_sizes, int n_in,
                              void* d_out, int out_size, void* d_ws, size_t ws_size,
                              hipStream_t stream) {
    const float* feat = (const float*)d_in[0];
    const float* W    = (const float*)d_in[1];
    const float* a    = (const float*)d_in[2];
    const float* bias = (const float*)d_in[3];
    const int*   adj  = (const int*)d_in[4];
    float* out = (float*)d_out;

    char* ws = (char*)d_ws;
    uint2* hb        = (uint2*)(ws);                    // 12,800,000 B (bf16 h)
    float* s_src     = (float*)(ws + 25600000);         //    200,000 B
    float* s_dst     = (float*)(ws + 25800000);         //    200,000 B
    int*   counts    = (int*)  (ws + 26000000);         //    200,000 B
    int*   row_start = (int*)  (ws + 26200000);         //    200,000 B
    int*   cursor    = (int*)  (ws + 26400000);         //    200,000 B
    int*   col       = (int*)  (ws + 26600000);         //  3,200,000 B
    int*   incl      = col;                             // aliased: dead before k_fill
    int*   bsum      = (int*)  (ws + 29800000);         //        784 B

    hipMemsetAsync(counts, 0, N_NODES * sizeof(int), stream);

    k_gemm_hist<<<FUSE_NBLK, 256, 0, stream>>>(feat, W, a, bias, hb, s_src, s_dst,
                                               adj, counts);
    k_scan1<<<SCAN_NBLK, 256, 0, stream>>>(counts, incl, bsum);
    k_scan3<<<SCAN_NBLK, 256, 0, stream>>>(incl, counts, bsum, row_start, cursor);
    k_fill<<<EDGE_NBLK * NXCD, 256, 0, stream>>>(adj, cursor, col);
    k_gather<<<N_NODES / 8, 256, 0, stream>>>(row_start, cursor, col,
                                              s_src, s_dst, hb, out);
}